// Round 2
// baseline (1280.120 us; speedup 1.0000x reference)
//
#include <hip/hip_runtime.h>
#include <cstdint>

typedef unsigned long long u64;

#define MAXN 20480
#define MAXNW 320
#define SORT_CHUNK 4096

// ---------------- init ----------------
__global__ void init_out_kernel(int* out, int n) {
    int i = blockIdx.x * blockDim.x + threadIdx.x;
    if (i < n) out[i] = 0;
}

// ---------------- key build ----------------
// key = (descending-orderable score | invalid->0xFFFFFFFF) << 32 | orig_idx
// ascending sort of key == stable descending sort by score (ties: lower idx first)
__global__ void build_keys_kernel(const float* __restrict__ scores,
                                  const float* __restrict__ scoreThrPtr,
                                  u64* __restrict__ keys, int N, int PAD) {
    int i = blockIdx.x * blockDim.x + threadIdx.x;
    if (i >= PAD) return;
    u64 key = ~0ull;
    if (i < N) {
        float s = scores[i];
        float thr = *scoreThrPtr;
        unsigned u = __float_as_uint(s);
        u ^= (u >> 31) ? 0xFFFFFFFFu : 0x80000000u;   // orderable ascending
        unsigned ud = ~u;                              // descending
        if (!(s > thr)) ud = 0xFFFFFFFFu;              // invalid -> end
        key = ((u64)ud << 32) | (unsigned)i;
    }
    keys[i] = key;
}

// ---------------- bitonic sort ----------------
__global__ __launch_bounds__(1024) void bitonic_local_full_kernel(u64* keys) {
    __shared__ u64 lk[SORT_CHUNK];
    int base = blockIdx.x * SORT_CHUNK;
    int t = threadIdx.x;
    for (int u = t; u < SORT_CHUNK; u += 1024) lk[u] = keys[base + u];
    __syncthreads();
    for (int k = 2; k <= SORT_CHUNK; k <<= 1) {
        for (int j = k >> 1; j > 0; j >>= 1) {
            for (int p = t; p < SORT_CHUNK / 2; p += 1024) {
                int i = ((p & ~(j - 1)) << 1) | (p & (j - 1));
                int l = i + j;
                bool up = (((base + i) & k) == 0);
                u64 a = lk[i], b = lk[l];
                if ((a > b) == up) { lk[i] = b; lk[l] = a; }
            }
            __syncthreads();
        }
    }
    for (int u = t; u < SORT_CHUNK; u += 1024) keys[base + u] = lk[u];
}

__global__ void bitonic_global_kernel(u64* keys, int k, int j) {
    int p = blockIdx.x * blockDim.x + threadIdx.x;
    int i = ((p & ~(j - 1)) << 1) | (p & (j - 1));
    int l = i + j;
    bool up = ((i & k) == 0);
    u64 a = keys[i], b = keys[l];
    if ((a > b) == up) { keys[i] = b; keys[l] = a; }
}

__global__ __launch_bounds__(1024) void bitonic_local_tail_kernel(u64* keys, int k) {
    __shared__ u64 lk[SORT_CHUNK];
    int base = blockIdx.x * SORT_CHUNK;
    int t = threadIdx.x;
    for (int u = t; u < SORT_CHUNK; u += 1024) lk[u] = keys[base + u];
    __syncthreads();
    for (int j = SORT_CHUNK / 2; j > 0; j >>= 1) {
        for (int p = t; p < SORT_CHUNK / 2; p += 1024) {
            int i = ((p & ~(j - 1)) << 1) | (p & (j - 1));
            int l = i + j;
            bool up = (((base + i) & k) == 0);
            u64 a = lk[i], b = lk[l];
            if ((a > b) == up) { lk[i] = b; lk[l] = a; }
        }
        __syncthreads();
    }
    for (int u = t; u < SORT_CHUNK; u += 1024) keys[base + u] = lk[u];
}

// ---------------- post-sort gather ----------------
__global__ void make_validw_kernel(const u64* __restrict__ keys,
                                   u64* __restrict__ validw, int N, int NW) {
    int w = blockIdx.x * blockDim.x + threadIdx.x;
    if (w >= NW) return;
    u64 bits = 0;
    for (int b = 0; b < 64; ++b) {
        int r = w * 64 + b;
        if (r < N && (unsigned)(keys[r] >> 32) != 0xFFFFFFFFu) bits |= 1ull << b;
    }
    validw[w] = bits;
}

__global__ void gather_kernel(const u64* __restrict__ keys, const float* __restrict__ boxes,
                              float* __restrict__ sx1, float* __restrict__ sy1,
                              float* __restrict__ sx2, float* __restrict__ sy2,
                              float* __restrict__ areas, int* __restrict__ sorig, int N) {
    int r = blockIdx.x * blockDim.x + threadIdx.x;
    if (r >= N) return;
    int idx = (int)(keys[r] & 0xFFFFFFFFu);
    float4 b = ((const float4*)boxes)[idx];
    sx1[r] = b.x; sy1[r] = b.y; sx2[r] = b.z; sy2[r] = b.w;
    areas[r] = (b.z - b.x) * (b.w - b.y);
    sorig[r] = idx;
}

// ---------------- pairwise IoU mask (upper triangle of 64x64 word tiles) ----------------
__global__ __launch_bounds__(64) void mask_kernel(
        const float* __restrict__ sx1, const float* __restrict__ sy1,
        const float* __restrict__ sx2, const float* __restrict__ sy2,
        const float* __restrict__ areas, const float* __restrict__ iouThrPtr,
        u64* __restrict__ mask, int N, int NW) {
    int wi = blockIdx.x, wj = blockIdx.y;
    if (wj < wi) return;
    __shared__ float jx1[64], jy1[64], jx2[64], jy2[64], ja[64];
    int t = threadIdx.x;
    int j0 = wj << 6;
    int jn = min(64, N - j0);
    if (t < jn) {
        jx1[t] = sx1[j0 + t]; jy1[t] = sy1[j0 + t];
        jx2[t] = sx2[j0 + t]; jy2[t] = sy2[j0 + t];
        ja[t] = areas[j0 + t];
    }
    __syncthreads();
    int i = (wi << 6) + t;
    if (i >= N) return;
    float thr = *iouThrPtr;
    float ix1 = sx1[i], iy1 = sy1[i], ix2 = sx2[i], iy2 = sy2[i], ia = areas[i];
    u64 bits = 0;
    for (int jj = 0; jj < jn; ++jj) {
        int j = j0 + jj;
        if (j > i) {
            float xx1 = fmaxf(ix1, jx1[jj]);
            float yy1 = fmaxf(iy1, jy1[jj]);
            float xx2 = fminf(ix2, jx2[jj]);
            float yy2 = fminf(iy2, jy2[jj]);
            float ww = fmaxf(xx2 - xx1, 0.0f);
            float hh = fmaxf(yy2 - yy1, 0.0f);
            float inter = ww * hh;
            float uni = fmaxf(ia + ja[jj] - inter, 1e-6f);
            if (inter / uni >= thr) bits |= 1ull << jj;
        }
    }
    mask[(size_t)i * NW + wj] = bits;
}

// ---------------- single-wave register-resident speculative scan ----------------
// S (suppressed bitset, 313 words) lives in VGPRs: lane l, reg r owns word w = r*64+l.
// Depth-4 pipeline: current row + 3 predicted rows in flight. Predictions are the
// next live bits of S; a prediction only dies if an intervening selected box
// overlaps it (IoU>=thr), which is rare -> ~95% hit rate.

__device__ __forceinline__ int findFirst(const u64 (&c)[5]) {
#pragma unroll
    for (int r = 0; r < 5; ++r) {
        u64 ball = __ballot(c[r] != 0ull);
        if (ball) {
            int l = (int)__builtin_ctzll(ball);
            u64 w = __shfl(c[r], l, 64);
            return (((r << 6) | l) << 6) | (int)__builtin_ctzll(w);
        }
    }
    return -1;
}

__device__ __forceinline__ void clearBit(u64 (&c)[5], int pos, int lane) {
    int rr = pos >> 12, l = (pos >> 6) & 63, b = pos & 63;
    if (lane == l) {
#pragma unroll
        for (int r = 0; r < 5; ++r) if (r == rr) c[r] &= ~(1ull << b);
    }
}

__device__ __forceinline__ void cpy5(u64 (&d)[5], const u64 (&s)[5]) {
#pragma unroll
    for (int r = 0; r < 5; ++r) d[r] = s[r];
}

__device__ __forceinline__ void issueRow(u64 (&R)[5], const u64* __restrict__ mask,
                                         size_t stride, int idx, int lane) {
    const u64* p = mask + (size_t)idx * stride + lane;
#pragma unroll
    for (int r = 0; r < 5; ++r) R[r] = p[r * 64];
}

__device__ __forceinline__ void applyRow(u64 (&S)[5], const u64 (&R)[5], u64 (&c)[5],
                                         int cur, int lane) {
#pragma unroll
    for (int r = 0; r < 5; ++r) S[r] |= R[r];
    int rr = cur >> 12, l = (cur >> 6) & 63, b = cur & 63;
    if (lane == l) {
#pragma unroll
        for (int r = 0; r < 5; ++r) if (r == rr) S[r] |= 1ull << b;
    }
#pragma unroll
    for (int r = 0; r < 5; ++r) c[r] = ~S[r];
}

__global__ __launch_bounds__(64) void nms_scan_wave_kernel(
        const u64* __restrict__ mask, const u64* __restrict__ validw,
        const int* __restrict__ sorig, int* __restrict__ out,
        int N, int NW, int maxOut) {
    __shared__ int selLDS[1024];
    int lane = threadIdx.x;
    size_t stride = (size_t)NW;

    u64 S[5], c[5];
#pragma unroll
    for (int r = 0; r < 5; ++r) {
        int w = r * 64 + lane;
        u64 v = (w < NW) ? validw[w] : 0ull;   // live mask
        S[r] = ~v;
        c[r] = v;
    }

    u64 rA[5], rB[5], rC[5], rD[5];
    int cnt = 0;
    int cur, spec1 = -1, spec2 = -1, spec3 = -1;

    cur = findFirst(c);
    if (cur >= 0) {
        issueRow(rA, mask, stride, cur, lane);
        u64 t[5]; cpy5(t, c); clearBit(t, cur, lane);
        spec1 = findFirst(t);
        if (spec1 >= 0) {
            issueRow(rB, mask, stride, spec1, lane); clearBit(t, spec1, lane);
            spec2 = findFirst(t);
            if (spec2 >= 0) {
                issueRow(rC, mask, stride, spec2, lane); clearBit(t, spec2, lane);
                spec3 = findFirst(t);
                if (spec3 >= 0) issueRow(rD, mask, stride, spec3, lane);
            }
        }
    }

    bool done = false;

#define BODY(RX, RY, RZ, RW)                                                  \
    if (cur < 0 || cnt >= maxOut) { done = true; }                            \
    else {                                                                    \
        if (lane == 0) selLDS[cnt] = cur;                                     \
        ++cnt;                                                                \
        applyRow(S, RX, c, cur, lane);                                        \
        int nxt = findFirst(c);                                               \
        if (nxt < 0) { cur = -1; }                                            \
        else if (nxt == spec1) {                                              \
            u64 t[5]; cpy5(t, c); clearBit(t, nxt, lane);                     \
            if (spec2 >= 0) clearBit(t, spec2, lane);                         \
            if (spec3 >= 0) clearBit(t, spec3, lane);                         \
            int p = findFirst(t);                                             \
            if (p >= 0) issueRow(RX, mask, stride, p, lane);                  \
            cur = nxt; spec1 = spec2; spec2 = spec3; spec3 = p;               \
        } else {                                                              \
            issueRow(RY, mask, stride, nxt, lane);                            \
            u64 t[5]; cpy5(t, c); clearBit(t, nxt, lane);                     \
            int p1 = findFirst(t);                                            \
            if (p1 >= 0) { issueRow(RZ, mask, stride, p1, lane); clearBit(t, p1, lane); } \
            int p2 = findFirst(t);                                            \
            if (p2 >= 0) { issueRow(RW, mask, stride, p2, lane); clearBit(t, p2, lane); } \
            int p3 = findFirst(t);                                            \
            if (p3 >= 0) issueRow(RX, mask, stride, p3, lane);                \
            cur = nxt; spec1 = p1; spec2 = p2; spec3 = p3;                    \
        }                                                                     \
    }

    while (!done) {
        BODY(rA, rB, rC, rD); if (done) break;
        BODY(rB, rC, rD, rA); if (done) break;
        BODY(rC, rD, rA, rB); if (done) break;
        BODY(rD, rA, rB, rC);
    }
#undef BODY

    for (int k = lane; k < cnt; k += 64) out[k] = sorig[selLDS[k]];
    if (lane == 0) out[maxOut] = cnt;
}

// ---------------- fallback: no-mask on-the-fly scan (if ws too small) ----------------
__global__ __launch_bounds__(MAXNW) void nms_scan_fly_kernel(
        const float* __restrict__ sx1, const float* __restrict__ sy1,
        const float* __restrict__ sx2, const float* __restrict__ sy2,
        const float* __restrict__ areas, const u64* __restrict__ validw,
        const int* __restrict__ sorig, const float* __restrict__ iouThrPtr,
        int* __restrict__ out, int N, int NW, int maxOut) {
    __shared__ u64 S[MAXNW];
    __shared__ int sh_i;
    __shared__ float bb[5];
    int t = threadIdx.x;
    for (int w = t; w < NW; w += MAXNW) S[w] = ~validw[w];
    __syncthreads();
    float thr = *iouThrPtr;
    int cnt = 0, w0 = 0;
    while (true) {
        if (t == 0) {
            int found = -1;
            if (cnt < maxOut) {
                while (w0 < NW) {
                    u64 c = ~S[w0];
                    if (c) { found = (w0 << 6) + __builtin_ctzll(c); break; }
                    ++w0;
                }
            }
            sh_i = found;
            if (found >= 0) {
                bb[0] = sx1[found]; bb[1] = sy1[found];
                bb[2] = sx2[found]; bb[3] = sy2[found]; bb[4] = areas[found];
            }
        }
        __syncthreads();
        int i = sh_i;
        if (i < 0) break;
        int wi = i >> 6;
        if (t == 0) { out[cnt] = sorig[i]; ++cnt; }
        for (int w = t; w < NW; w += MAXNW) {
            if (w < wi) continue;
            u64 bits = (w == wi) ? (1ull << (i & 63)) : 0;
            int j0 = w << 6, jn = min(64, N - j0);
            for (int jj = 0; jj < jn; ++jj) {
                int j = j0 + jj;
                if (j > i) {
                    float xx1 = fmaxf(bb[0], sx1[j]);
                    float yy1 = fmaxf(bb[1], sy1[j]);
                    float xx2 = fminf(bb[2], sx2[j]);
                    float yy2 = fminf(bb[3], sy2[j]);
                    float ww = fmaxf(xx2 - xx1, 0.0f);
                    float hh = fmaxf(yy2 - yy1, 0.0f);
                    float inter = ww * hh;
                    float uni = fmaxf(bb[4] + areas[j] - inter, 1e-6f);
                    if (inter / uni >= thr) bits |= 1ull << jj;
                }
            }
            S[w] |= bits;
        }
        __syncthreads();
    }
    if (t == 0) out[maxOut] = cnt;
}

// ---------------- launch ----------------
extern "C" void kernel_launch(void* const* d_in, const int* in_sizes, int n_in,
                              void* d_out, int out_size, void* d_ws, size_t ws_size,
                              hipStream_t stream) {
    const float* boxes      = (const float*)d_in[0];
    const float* scores     = (const float*)d_in[1];
    const float* iouThrPtr  = (const float*)d_in[3];
    const float* scoreThrPtr= (const float*)d_in[4];

    int N  = in_sizes[0] / 4;
    int NW = (N + 63) / 64;
    int NW64 = NW * 64;
    int maxOut = out_size - 1;
    int PAD = SORT_CHUNK; while (PAD < N) PAD <<= 1;

    char* ws = (char*)d_ws;
    size_t off = 0;
    auto take = [&](size_t b) { void* p = ws + off; off = (off + b + 255) & ~(size_t)255; return p; };
    u64*   keys   = (u64*)  take((size_t)PAD * 8);
    float* sx1    = (float*)take((size_t)NW64 * 4);
    float* sy1    = (float*)take((size_t)NW64 * 4);
    float* sx2    = (float*)take((size_t)NW64 * 4);
    float* sy2    = (float*)take((size_t)NW64 * 4);
    float* areas  = (float*)take((size_t)NW64 * 4);
    int*   sorig  = (int*)  take((size_t)NW64 * 4);
    u64*   validw = (u64*)  take((size_t)NW * 8);
    // +64B pad: the wave scan reads up to 7 words past each row (harmless, OR'd
    // into already-all-ones pad words of S), and past the last row end.
    u64*   mask   = (u64*)  take((size_t)N * NW * 8 + 64);
    bool useMask = (off <= ws_size);

    init_out_kernel<<<(out_size + 255) / 256, 256, 0, stream>>>((int*)d_out, out_size);
    build_keys_kernel<<<(PAD + 255) / 256, 256, 0, stream>>>(scores, scoreThrPtr, keys, N, PAD);

    bitonic_local_full_kernel<<<PAD / SORT_CHUNK, 1024, 0, stream>>>(keys);
    for (int k = SORT_CHUNK * 2; k <= PAD; k <<= 1) {
        for (int j = k >> 1; j >= SORT_CHUNK; j >>= 1)
            bitonic_global_kernel<<<PAD / 2 / 256, 256, 0, stream>>>(keys, k, j);
        bitonic_local_tail_kernel<<<PAD / SORT_CHUNK, 1024, 0, stream>>>(keys, k);
    }

    make_validw_kernel<<<(NW + 63) / 64, 64, 0, stream>>>(keys, validw, N, NW);
    gather_kernel<<<(N + 255) / 256, 256, 0, stream>>>(keys, boxes, sx1, sy1, sx2, sy2, areas, sorig, N);

    if (useMask) {
        mask_kernel<<<dim3(NW, NW), 64, 0, stream>>>(sx1, sy1, sx2, sy2, areas, iouThrPtr, mask, N, NW);
        nms_scan_wave_kernel<<<1, 64, 0, stream>>>(mask, validw, sorig, (int*)d_out, N, NW, maxOut);
    } else {
        nms_scan_fly_kernel<<<1, MAXNW, 0, stream>>>(sx1, sy1, sx2, sy2, areas, validw, sorig,
                                                     iouThrPtr, (int*)d_out, N, NW, maxOut);
    }
}

// Round 3
// 178.984 us; speedup vs baseline: 7.1521x; 7.1521x over previous
//
#include <hip/hip_runtime.h>
#include <cstdint>

typedef unsigned long long u64;

#define MAXNW 320
#define SORT_CHUNK 4096
#define MCAP 2048          // fast-path candidate cap (multiple of 64)
#define SCAN_T 256

// ---------------- key build ----------------
// key = (descending-orderable score | invalid->0xFFFFFFFF) << 32 | orig_idx
__global__ void build_keys_kernel(const float* __restrict__ scores,
                                  const float* __restrict__ scoreThrPtr,
                                  u64* __restrict__ keys, int N, int PAD) {
    int i = blockIdx.x * blockDim.x + threadIdx.x;
    if (i >= PAD) return;
    u64 key = ~0ull;
    if (i < N) {
        float s = scores[i];
        float thr = *scoreThrPtr;
        unsigned u = __float_as_uint(s);
        u ^= (u >> 31) ? 0xFFFFFFFFu : 0x80000000u;
        unsigned ud = ~u;
        if (!(s > thr)) ud = 0xFFFFFFFFu;
        key = ((u64)ud << 32) | (unsigned)i;
    }
    keys[i] = key;
}

// ---------------- bitonic sort ----------------
__global__ __launch_bounds__(1024) void bitonic_local_full_kernel(u64* keys) {
    __shared__ u64 lk[SORT_CHUNK];
    int base = blockIdx.x * SORT_CHUNK;
    int t = threadIdx.x;
    for (int u = t; u < SORT_CHUNK; u += 1024) lk[u] = keys[base + u];
    __syncthreads();
    for (int k = 2; k <= SORT_CHUNK; k <<= 1) {
        for (int j = k >> 1; j > 0; j >>= 1) {
            for (int p = t; p < SORT_CHUNK / 2; p += 1024) {
                int i = ((p & ~(j - 1)) << 1) | (p & (j - 1));
                int l = i + j;
                bool up = (((base + i) & k) == 0);
                u64 a = lk[i], b = lk[l];
                if ((a > b) == up) { lk[i] = b; lk[l] = a; }
            }
            __syncthreads();
        }
    }
    for (int u = t; u < SORT_CHUNK; u += 1024) keys[base + u] = lk[u];
}

__global__ void bitonic_global_kernel(u64* keys, int k, int j) {
    int p = blockIdx.x * blockDim.x + threadIdx.x;
    int i = ((p & ~(j - 1)) << 1) | (p & (j - 1));
    int l = i + j;
    bool up = ((i & k) == 0);
    u64 a = keys[i], b = keys[l];
    if ((a > b) == up) { keys[i] = b; keys[l] = a; }
}

__global__ __launch_bounds__(1024) void bitonic_local_tail_kernel(u64* keys, int k) {
    __shared__ u64 lk[SORT_CHUNK];
    int base = blockIdx.x * SORT_CHUNK;
    int t = threadIdx.x;
    for (int u = t; u < SORT_CHUNK; u += 1024) lk[u] = keys[base + u];
    __syncthreads();
    for (int j = SORT_CHUNK / 2; j > 0; j >>= 1) {
        for (int p = t; p < SORT_CHUNK / 2; p += 1024) {
            int i = ((p & ~(j - 1)) << 1) | (p & (j - 1));
            int l = i + j;
            bool up = (((base + i) & k) == 0);
            u64 a = lk[i], b = lk[l];
            if ((a > b) == up) { lk[i] = b; lk[l] = a; }
        }
        __syncthreads();
    }
    for (int u = t; u < SORT_CHUNK; u += 1024) keys[base + u] = lk[u];
}

// ---------------- post-sort gather (+ validw via ballot) ----------------
__global__ void gather_kernel(const u64* __restrict__ keys, const float* __restrict__ boxes,
                              float* __restrict__ sx1, float* __restrict__ sy1,
                              float* __restrict__ sx2, float* __restrict__ sy2,
                              float* __restrict__ areas, int* __restrict__ sorig,
                              u64* __restrict__ validw, int N) {
    int r = blockIdx.x * 256 + threadIdx.x;
    bool inb = r < N;
    unsigned hi = 0xFFFFFFFFu;
    unsigned lo = 0;
    if (inb) { u64 k = keys[r]; hi = (unsigned)(k >> 32); lo = (unsigned)k; }
    bool valid = inb && hi != 0xFFFFFFFFu;
    u64 ball = __ballot(valid);
    if (((threadIdx.x & 63) == 0) && inb) validw[r >> 6] = ball;
    if (inb) {
        float4 b = ((const float4*)boxes)[lo];
        sx1[r] = b.x; sy1[r] = b.y; sx2[r] = b.z; sy2[r] = b.w;
        areas[r] = (b.z - b.x) * (b.w - b.y);
        sorig[r] = (int)lo;
    }
}

// ---------------- small IoU mask over top-Mn candidates (+ transposed diagonal) ----
__global__ __launch_bounds__(64) void mask2_kernel(
        const float* __restrict__ sx1, const float* __restrict__ sy1,
        const float* __restrict__ sx2, const float* __restrict__ sy2,
        const float* __restrict__ areas, const float* __restrict__ iouThrPtr,
        u64* __restrict__ mask2, u64* __restrict__ diagT, int Mn, int MW) {
    int wi = blockIdx.x, wj = blockIdx.y;
    if (wj < wi) return;                       // uniform block exit (before barriers)
    __shared__ float jx1[64], jy1[64], jx2[64], jy2[64], ja[64];
    __shared__ u64 rowLDS[64];
    int t = threadIdx.x;
    int j0 = wj << 6;
    int jn = min(64, Mn - j0);
    if (t < jn) {
        jx1[t] = sx1[j0 + t]; jy1[t] = sy1[j0 + t];
        jx2[t] = sx2[j0 + t]; jy2[t] = sy2[j0 + t];
        ja[t] = areas[j0 + t];
    }
    __syncthreads();
    int i = (wi << 6) + t;
    u64 bits = 0;
    if (i < Mn) {
        float thr = *iouThrPtr;
        float ix1 = sx1[i], iy1 = sy1[i], ix2 = sx2[i], iy2 = sy2[i], ia = areas[i];
        for (int jj = 0; jj < jn; ++jj) {
            int j = j0 + jj;
            if (j > i) {
                float xx1 = fmaxf(ix1, jx1[jj]);
                float yy1 = fmaxf(iy1, jy1[jj]);
                float xx2 = fminf(ix2, jx2[jj]);
                float yy2 = fminf(iy2, jy2[jj]);
                float ww = fmaxf(xx2 - xx1, 0.0f);
                float hh = fmaxf(yy2 - yy1, 0.0f);
                float inter = ww * hh;
                float uni = fmaxf(ia + ja[jj] - inter, 1e-6f);
                if (inter / uni >= thr) bits |= 1ull << jj;
            }
        }
        mask2[(size_t)i * MW + wj] = bits;
    }
    if (wi == wj) {                            // write transposed diagonal tile
        rowLDS[t] = bits;                      // rows i>=Mn contribute 0
        __syncthreads();
        u64 col = 0;
        for (int r = 0; r < 64; ++r) col |= ((rowLDS[r] >> t) & 1ull) << r;
        diagT[(wi << 6) + t] = col;            // bit r of col t: r suppresses t
    }
}

// ---------------- chunk-wise greedy scan over the small mask ----------------
__global__ __launch_bounds__(SCAN_T) void scan2_kernel(
        const u64* __restrict__ mask2, const u64* __restrict__ diagT,
        const u64* __restrict__ validw, const int* __restrict__ sorig,
        int* __restrict__ out, int* __restrict__ flagDone,
        int N, int NW, int Mn, int MW, int maxOut) {
    __shared__ int selLDS[MCAP];
    __shared__ u64 partLDS[SCAN_T / 64];
    __shared__ u64 validwLDS[MCAP / 64];
    __shared__ int cntLDS;
    __shared__ int anyBeyondLDS;
    int tid = threadIdx.x, lane = tid & 63, wave = tid >> 6;

    for (int w = tid; w < MW; w += SCAN_T) validwLDS[w] = validw[w];
    if (tid == 0) { cntLDS = 0; anyBeyondLDS = 0; }
    __syncthreads();

    int cnt = 0;
    for (int w = 0; w < MW; ++w) {
        u64 col = 0;
        if (wave == 0) col = diagT[(w << 6) + lane];           // issue early
        u64 part = 0;
        for (int k = tid; k < cnt; k += SCAN_T)
            part |= mask2[(size_t)selLDS[k] * MW + w];
#pragma unroll
        for (int off = 32; off >= 1; off >>= 1) part |= __shfl_xor(part, off, 64);
        if (lane == 0) partLDS[wave] = part;
        __syncthreads();
        if (wave == 0) {
            u64 Sw = ~validwLDS[w];
#pragma unroll
            for (int p = 0; p < SCAN_T / 64; ++p) Sw |= partLDS[p];
            bool alive = !((Sw >> lane) & 1ull);
            u64 c = __ballot(alive);
            u64 selmask = 0;
            int room = maxOut - cnt;
            while (c != 0ull && room > 0) {
                int b = __builtin_ctzll(c);
                selmask |= 1ull << b; --room;
                alive = alive && !((col >> b) & 1ull);
                u64 rest = (b >= 63) ? 0ull : ~((2ull << b) - 1ull);
                c = __ballot(alive) & rest;
            }
            if ((selmask >> lane) & 1ull) {
                int pos = cnt + __popcll(selmask & ((1ull << lane) - 1ull));
                selLDS[pos] = (w << 6) + lane;
            }
            if (lane == 0) cntLDS = cnt + __popcll(selmask);
        }
        __syncthreads();
        cnt = cntLDS;
        if (cnt >= maxOut) break;
    }

    bool complete = (cnt >= maxOut);
    if (!complete) {                                           // uniform branch
        int any = 0;
        for (int w = MW + tid; w < NW; w += SCAN_T) any |= (validw[w] != 0ull);
        if (any) anyBeyondLDS = 1;
        __syncthreads();
        complete = (anyBeyondLDS == 0);
    }
    if (complete) {
        for (int k = tid; k < cnt; k += SCAN_T) out[k] = sorig[selLDS[k]];
        for (int k = cnt + tid; k < maxOut; k += SCAN_T) out[k] = 0;
        if (tid == 0) out[maxOut] = cnt;
    }
    if (tid == 0) *flagDone = complete ? 1 : 0;
}

// ---------------- fallback: mask-free full scan (runs only if flag==0) -------
__global__ __launch_bounds__(MAXNW) void nms_scan_fly_kernel(
        const float* __restrict__ sx1, const float* __restrict__ sy1,
        const float* __restrict__ sx2, const float* __restrict__ sy2,
        const float* __restrict__ areas, const u64* __restrict__ validw,
        const int* __restrict__ sorig, const float* __restrict__ iouThrPtr,
        const int* __restrict__ flagDone,
        int* __restrict__ out, int N, int NW, int maxOut) {
    if (*flagDone) return;                     // uniform early-exit, before barriers
    __shared__ u64 S[MAXNW];
    __shared__ int sh_i;
    __shared__ int shCnt;
    __shared__ float bb[5];
    int t = threadIdx.x;
    for (int w = t; w < NW; w += MAXNW) S[w] = ~validw[w];
    __syncthreads();
    float thr = *iouThrPtr;
    int cnt = 0, w0 = 0;
    while (true) {
        if (t == 0) {
            int found = -1;
            if (cnt < maxOut) {
                while (w0 < NW) {
                    u64 c = ~S[w0];
                    if (c) { found = (w0 << 6) + __builtin_ctzll(c); break; }
                    ++w0;
                }
            }
            sh_i = found;
            if (found >= 0) {
                bb[0] = sx1[found]; bb[1] = sy1[found];
                bb[2] = sx2[found]; bb[3] = sy2[found]; bb[4] = areas[found];
            }
        }
        __syncthreads();
        int i = sh_i;
        if (i < 0) break;
        int wi = i >> 6;
        if (t == 0) { out[cnt] = sorig[i]; ++cnt; }
        for (int w = t; w < NW; w += MAXNW) {
            if (w < wi) continue;
            u64 bits = (w == wi) ? (1ull << (i & 63)) : 0;
            int j0 = w << 6, jn = min(64, N - j0);
            for (int jj = 0; jj < jn; ++jj) {
                int j = j0 + jj;
                if (j > i) {
                    float xx1 = fmaxf(bb[0], sx1[j]);
                    float yy1 = fmaxf(bb[1], sy1[j]);
                    float xx2 = fminf(bb[2], sx2[j]);
                    float yy2 = fminf(bb[3], sy2[j]);
                    float ww = fmaxf(xx2 - xx1, 0.0f);
                    float hh = fmaxf(yy2 - yy1, 0.0f);
                    float inter = ww * hh;
                    float uni = fmaxf(bb[4] + areas[j] - inter, 1e-6f);
                    if (inter / uni >= thr) bits |= 1ull << jj;
                }
            }
            S[w] |= bits;
        }
        __syncthreads();
    }
    if (t == 0) shCnt = cnt;
    __syncthreads();
    for (int k = shCnt + t; k < maxOut; k += MAXNW) out[k] = 0;
    if (t == 0) out[maxOut] = shCnt;
}

// ---------------- launch ----------------
extern "C" void kernel_launch(void* const* d_in, const int* in_sizes, int n_in,
                              void* d_out, int out_size, void* d_ws, size_t ws_size,
                              hipStream_t stream) {
    const float* boxes      = (const float*)d_in[0];
    const float* scores     = (const float*)d_in[1];
    const float* iouThrPtr  = (const float*)d_in[3];
    const float* scoreThrPtr= (const float*)d_in[4];

    int N  = in_sizes[0] / 4;
    int NW = (N + 63) / 64;
    int NW64 = NW * 64;
    int maxOut = out_size - 1;
    int PAD = SORT_CHUNK; while (PAD < N) PAD <<= 1;
    int Mn = (N < MCAP) ? N : MCAP;
    int MW = (Mn + 63) / 64;

    char* ws = (char*)d_ws;
    size_t off = 0;
    auto take = [&](size_t b) { void* p = ws + off; off = (off + b + 255) & ~(size_t)255; return p; };
    u64*   keys   = (u64*)  take((size_t)PAD * 8);
    float* sx1    = (float*)take((size_t)NW64 * 4);
    float* sy1    = (float*)take((size_t)NW64 * 4);
    float* sx2    = (float*)take((size_t)NW64 * 4);
    float* sy2    = (float*)take((size_t)NW64 * 4);
    float* areas  = (float*)take((size_t)NW64 * 4);
    int*   sorig  = (int*)  take((size_t)NW64 * 4);
    u64*   validw = (u64*)  take((size_t)NW * 8);
    u64*   mask2  = (u64*)  take((size_t)Mn * MW * 8);
    u64*   diagT  = (u64*)  take((size_t)MW * 64 * 8);
    int*   flag   = (int*)  take(256);
    (void)ws_size;

    build_keys_kernel<<<(PAD + 255) / 256, 256, 0, stream>>>(scores, scoreThrPtr, keys, N, PAD);

    bitonic_local_full_kernel<<<PAD / SORT_CHUNK, 1024, 0, stream>>>(keys);
    for (int k = SORT_CHUNK * 2; k <= PAD; k <<= 1) {
        for (int j = k >> 1; j >= SORT_CHUNK; j >>= 1)
            bitonic_global_kernel<<<PAD / 2 / 256, 256, 0, stream>>>(keys, k, j);
        bitonic_local_tail_kernel<<<PAD / SORT_CHUNK, 1024, 0, stream>>>(keys, k);
    }

    gather_kernel<<<(N + 255) / 256, 256, 0, stream>>>(keys, boxes, sx1, sy1, sx2, sy2,
                                                       areas, sorig, validw, N);

    mask2_kernel<<<dim3(MW, MW), 64, 0, stream>>>(sx1, sy1, sx2, sy2, areas, iouThrPtr,
                                                  mask2, diagT, Mn, MW);

    scan2_kernel<<<1, SCAN_T, 0, stream>>>(mask2, diagT, validw, sorig,
                                           (int*)d_out, flag, N, NW, Mn, MW, maxOut);

    nms_scan_fly_kernel<<<1, MAXNW, 0, stream>>>(sx1, sy1, sx2, sy2, areas, validw, sorig,
                                                 iouThrPtr, flag, (int*)d_out, N, NW, maxOut);
}